// Round 2
// baseline (493.652 us; speedup 1.0000x reference)
//
#include <hip/hip_runtime.h>

#define IN_F 128
#define OUT_F 32

// ---- CSR build ----------------------------------------------------------

// cnt[dst[e]]++
__global__ void k_hist(const int* __restrict__ dst, int* __restrict__ cnt, int E) {
    int e = blockIdx.x * blockDim.x + threadIdx.x;
    if (e < E) atomicAdd(&cnt[dst[e]], 1);
}

// per-block exclusive scan of cnt -> off (partial), block totals -> bsum,
// dis[i] = rsqrt(cnt[i]+1)  (+1 = self loop)
__global__ void k_scanA(const int* __restrict__ cnt, int* __restrict__ off,
                        int* __restrict__ bsum, float* __restrict__ dis, int n) {
    __shared__ int s[256];
    int t = threadIdx.x;
    int i = blockIdx.x * 256 + t;
    int v = (i < n) ? cnt[i] : 0;
    s[t] = v;
    __syncthreads();
    #pragma unroll
    for (int d = 1; d < 256; d <<= 1) {
        int add = (t >= d) ? s[t - d] : 0;
        __syncthreads();
        s[t] += add;
        __syncthreads();
    }
    if (i < n) {
        off[i] = s[t] - v;               // exclusive within block
        dis[i] = rsqrtf((float)(v + 1));
    }
    if (t == 255) bsum[blockIdx.x] = s[255];
}

// single-block exclusive scan of bsum (nb <= 512)
__global__ void k_scanB(int* __restrict__ bsum, int nb) {
    __shared__ int s[512];
    int t = threadIdx.x;
    int v = (t < nb) ? bsum[t] : 0;
    s[t] = v;
    __syncthreads();
    #pragma unroll
    for (int d = 1; d < 512; d <<= 1) {
        int add = (t >= d) ? s[t - d] : 0;
        __syncthreads();
        s[t] += add;
        __syncthreads();
    }
    if (t < nb) bsum[t] = s[t] - v;      // exclusive
}

// off[i] += bsum[block]; cursor[i] = off[i]; off[n] = E
__global__ void k_scanC(const int* __restrict__ cnt, int* __restrict__ off,
                        const int* __restrict__ bsum, int* __restrict__ cursor, int n) {
    int t = threadIdx.x;
    int i = blockIdx.x * 256 + t;
    if (i < n) {
        int o = off[i] + bsum[blockIdx.x];
        off[i] = o;
        cursor[i] = o;
        if (i == n - 1) off[n] = o + cnt[i];
    }
}

// csr[cursor[dst[e]]++] = src[e]
__global__ void k_fill(const int* __restrict__ src, const int* __restrict__ dst,
                       int* __restrict__ cursor, int* __restrict__ csr, int E) {
    int e = blockIdx.x * blockDim.x + threadIdx.x;
    if (e < E) {
        int pos = atomicAdd(&cursor[dst[e]], 1);
        csr[pos] = src[e];
    }
}

// ---- g = (x @ W^T) * dis ------------------------------------------------
// block = 256 threads = 8 nodes x 32 features
__global__ void k_gemm(const float* __restrict__ x, const float* __restrict__ W,
                       const float* __restrict__ dis, float* __restrict__ g, int n) {
    __shared__ float  Wl[IN_F * OUT_F];   // transposed: Wl[k*32 + f]
    __shared__ float4 xl4[8 * 32];        // 8 rows x 128 floats

    int tid = threadIdx.x;
    for (int i = tid; i < IN_F * OUT_F; i += 256) {
        int f = i >> 7;        // row of W (OUT_F)
        int k = i & 127;       // col of W (IN_F)
        Wl[k * 32 + f] = W[i];
    }

    int nodeBase = blockIdx.x * 8;
    int row = tid >> 5, c4 = tid & 31;
    int nrow = nodeBase + row;
    if (nrow < n) xl4[row * 32 + c4] = ((const float4*)x)[nrow * 32 + c4];
    __syncthreads();

    int f = tid & 31, nl = tid >> 5;
    int node = nodeBase + nl;
    if (node < n) {
        float acc = 0.f;
        #pragma unroll
        for (int k4 = 0; k4 < 32; ++k4) {
            float4 xv = xl4[nl * 32 + k4];
            int kb = k4 * 4;
            acc = fmaf(xv.x, Wl[(kb + 0) * 32 + f], acc);
            acc = fmaf(xv.y, Wl[(kb + 1) * 32 + f], acc);
            acc = fmaf(xv.z, Wl[(kb + 2) * 32 + f], acc);
            acc = fmaf(xv.w, Wl[(kb + 3) * 32 + f], acc);
        }
        g[node * OUT_F + f] = acc * dis[node];
    }
}

// ---- pull aggregation ---------------------------------------------------
// out[i][f] = dis[i] * ( g[i][f] + sum_{s in csr row i} g[s][f] ) + b[f]
__global__ void k_pull(const float* __restrict__ g, const int* __restrict__ off,
                       const int* __restrict__ csr, const float* __restrict__ dis,
                       const float* __restrict__ b, float* __restrict__ out, int n) {
    int tid = threadIdx.x;
    int node = blockIdx.x * 8 + (tid >> 5);
    int f = tid & 31;
    if (node < n) {
        int j0 = off[node], j1 = off[node + 1];
        float acc = g[node * OUT_F + f];        // self-loop message
        for (int j = j0; j < j1; ++j) {
            int s = csr[j];                     // broadcast within 32-lane group
            acc += g[s * OUT_F + f];            // 128B coalesced gather
        }
        out[node * OUT_F + f] = dis[node] * acc + b[f];
    }
}

extern "C" void kernel_launch(void* const* d_in, const int* in_sizes, int n_in,
                              void* d_out, int out_size, void* d_ws, size_t ws_size,
                              hipStream_t stream) {
    const float* x  = (const float*)d_in[0];
    const int*   ei = (const int*)d_in[1];
    const float* W  = (const float*)d_in[2];
    const float* b  = (const float*)d_in[3];
    float* out = (float*)d_out;

    int N = in_sizes[0] / IN_F;   // 100000
    int E = in_sizes[1] / 2;      // 1600000
    const int* src = ei;
    const int* dst = ei + E;

    // workspace layout
    char* p = (char*)d_ws;
    int*   cnt    = (int*)p;            p += (size_t)N * 4;
    int*   off    = (int*)p;            p += (size_t)(N + 1) * 4;
    int*   cursor = (int*)p;            p += (size_t)N * 4;
    int*   bsum   = (int*)p;            p += 512 * 4;
    float* dis    = (float*)p;          p += (size_t)N * 4;
    float* g      = (float*)p;          p += (size_t)N * OUT_F * 4;
    int*   csr    = (int*)p;            p += (size_t)E * 4;

    int nbScan = (N + 255) / 256;       // 391

    hipMemsetAsync(cnt, 0, (size_t)N * 4, stream);
    k_hist <<<(E + 255) / 256, 256, 0, stream>>>(dst, cnt, E);
    k_scanA<<<nbScan, 256, 0, stream>>>(cnt, off, bsum, dis, N);
    k_scanB<<<1, 512, 0, stream>>>(bsum, nbScan);
    k_scanC<<<nbScan, 256, 0, stream>>>(cnt, off, bsum, cursor, N);
    k_fill <<<(E + 255) / 256, 256, 0, stream>>>(src, dst, cursor, csr, E);
    k_gemm <<<(N + 7) / 8, 256, 0, stream>>>(x, W, dis, g, N);
    k_pull <<<(N + 7) / 8, 256, 0, stream>>>(g, off, csr, dis, b, out, N);
}